// Round 1
// baseline (198.636 us; speedup 1.0000x reference)
//
#include <hip/hip_runtime.h>
#include <hip/hip_bf16.h>

#define S_LEN 2048
#define DM    512
#define NH    8
#define DH    64

typedef float  f4  __attribute__((ext_vector_type(4)));
typedef short  s8v __attribute__((ext_vector_type(8)));
typedef __bf16 b8v __attribute__((ext_vector_type(8)));
union F8 { s8v s; b8v b; };

typedef __attribute__((address_space(1))) const void gas_t;
typedef __attribute__((address_space(3))) void       las_t;

__device__ __forceinline__ void gl16(const void* g, void* l) {
  __builtin_amdgcn_global_load_lds((gas_t*)g, (las_t*)l, 16, 0, 0);
}

__device__ __forceinline__ ushort f2bf(float x) {
  unsigned u = __float_as_uint(x);
  u += 0x7FFFu + ((u >> 16) & 1u);   // round-to-nearest-even
  return (ushort)(u >> 16);
}
__device__ __forceinline__ unsigned pack2(float a, float b) {
  return (unsigned)f2bf(a) | ((unsigned)f2bf(b) << 16);
}

// ---------------- mask scan: flag = any(mask != 0) ----------------
__global__ void mask_scan(const float* __restrict__ m, int* __restrict__ flag) {
  const int i = blockIdx.x * 256 + threadIdx.x;
  const float4 v = ((const float4*)m)[i];
  const bool nz = (v.x != 0.f) | (v.y != 0.f) | (v.z != 0.f) | (v.w != 0.f);
  if (nz) atomicOr(flag, 1);
}

// ---------------- fp32 -> bf16 convert (q,k,v) ----------------
__global__ void cvt3(const float* __restrict__ q, const float* __restrict__ k,
                     const float* __restrict__ v, ushort* __restrict__ oq,
                     ushort* __restrict__ ok, ushort* __restrict__ ov) {
  const int z = blockIdx.y;
  const float* s = (z == 0) ? q : (z == 1) ? k : v;
  ushort* d = (z == 0) ? oq : (z == 1) ? ok : ov;
  const size_t i = ((size_t)blockIdx.x * 256 + threadIdx.x) * 8;
  const float4 a = *(const float4*)(s + i);
  const float4 b = *(const float4*)(s + i + 4);
  s8v r;
  r[0] = (short)f2bf(a.x); r[1] = (short)f2bf(a.y);
  r[2] = (short)f2bf(a.z); r[3] = (short)f2bf(a.w);
  r[4] = (short)f2bf(b.x); r[5] = (short)f2bf(b.y);
  r[6] = (short)f2bf(b.z); r[7] = (short)f2bf(b.w);
  *(s8v*)(d + i) = r;
}

// ------------- weight transpose+convert: Wt[n][k] = bf16(W[k][n]) -------------
__global__ void wtrans(const float* __restrict__ w0, const float* __restrict__ w1,
                       const float* __restrict__ w2, const float* __restrict__ w3,
                       ushort* __restrict__ o0, ushort* __restrict__ o1,
                       ushort* __restrict__ o2, ushort* __restrict__ o3) {
  const int z = blockIdx.z;
  const float* src = (z == 0) ? w0 : (z == 1) ? w1 : (z == 2) ? w2 : w3;
  ushort* dst = (z == 0) ? o0 : (z == 1) ? o1 : (z == 2) ? o2 : o3;
  __shared__ float tile[32][33];
  const int tx = threadIdx.x, ty = threadIdx.y;    // 32 x 8
  const int k0 = blockIdx.x * 32, n0 = blockIdx.y * 32;
#pragma unroll
  for (int i = 0; i < 4; ++i)
    tile[ty + i * 8][tx] = src[(size_t)(k0 + ty + i * 8) * DM + n0 + tx];
  __syncthreads();
#pragma unroll
  for (int i = 0; i < 4; ++i)
    dst[(size_t)(n0 + ty + i * 8) * DM + k0 + tx] = f2bf(tile[tx][ty + i * 8]);
}

// ---------------- 128x128 bf16 MFMA GEMM core (M=8192,N=512,K=512) ----------------
// mode 0: out bf16 [B,H,S,64] head-split; mode 1: out bf16 [B,H,64,S] (V^T);
// mode 2: out fp32 [M,N]
__device__ __forceinline__ void gemm_core(
    const ushort* __restrict__ A, const ushort* __restrict__ Bt,
    const float* __restrict__ bias, void* __restrict__ out, int mode,
    ushort* As, ushort* Bs) {
  const int tid  = threadIdx.x;
  const int lane = tid & 63, wave = tid >> 6;
  const int ql = lane & 15, lg = lane >> 4;
  const int wr = wave >> 1, wc = wave & 1;
  const int tm = blockIdx.x, tn = blockIdx.y;

  const int srow  = wave * 32 + (lane >> 2);       // staging row (this call)
  const int sbyte = (lane & 3) * 16;               // byte within 64B row chunk

  const char* gA = (const char*)(A  + (size_t)(tm * 128 + srow) * 512) + sbyte;
  const char* gB = (const char*)(Bt + (size_t)(tn * 128 + srow) * 512) + sbyte;
  char* lA = (char*)As + wave * 2048;
  char* lB = (char*)Bs + wave * 2048;

  f4 acc[4][4] = {};

  for (int kt = 0; kt < 16; ++kt) {
    const size_t gofs = (size_t)kt * 64;           // 32 elems * 2B
    gl16(gA + gofs, lA);
    gl16(gA + gofs + 16 * 512 * 2, lA + 1024);
    gl16(gB + gofs, lB);
    gl16(gB + gofs + 16 * 512 * 2, lB + 1024);
    __syncthreads();
    F8 af[4], bf[4];
#pragma unroll
    for (int i = 0; i < 4; ++i) {
      af[i].s = *(const s8v*)(As + (wr * 64 + i * 16 + ql) * 32 + lg * 8);
      bf[i].s = *(const s8v*)(Bs + (wc * 64 + i * 16 + ql) * 32 + lg * 8);
    }
#pragma unroll
    for (int i = 0; i < 4; ++i)
#pragma unroll
      for (int j = 0; j < 4; ++j)
        acc[i][j] = __builtin_amdgcn_mfma_f32_16x16x32_bf16(af[i].b, bf[j].b,
                                                            acc[i][j], 0, 0, 0);
    __syncthreads();
  }

#pragma unroll
  for (int i = 0; i < 4; ++i) {
#pragma unroll
    for (int j = 0; j < 4; ++j) {
      const int n = tn * 128 + wc * 64 + j * 16 + ql;
      const float bz = bias[n];
#pragma unroll
      for (int r = 0; r < 4; ++r) {
        const int m = tm * 128 + wr * 64 + i * 16 + lg * 4 + r;
        const float val = acc[i][j][r] + bz;
        if (mode == 2) {
          ((float*)out)[(size_t)m * DM + n] = val;
        } else {
          const int b = m >> 11, s = m & 2047, h = n >> 6, d = n & 63;
          if (mode == 0)
            ((ushort*)out)[((size_t)(b * NH + h) * S_LEN + s) * DH + d] = f2bf(val);
          else
            ((ushort*)out)[((size_t)(b * NH + h) * DH + d) * S_LEN + s] = f2bf(val);
        }
      }
    }
  }
}

__global__ __launch_bounds__(256) void gemm_qkv(
    const ushort* __restrict__ Xq, const ushort* __restrict__ Xk,
    const ushort* __restrict__ Xv, const ushort* __restrict__ Wtq,
    const ushort* __restrict__ Wtk, const ushort* __restrict__ Wtv,
    const float* __restrict__ bq, const float* __restrict__ bk,
    const float* __restrict__ bv, ushort* __restrict__ Qh,
    ushort* __restrict__ Kh, ushort* __restrict__ Vt) {
  __shared__ ushort As[128 * 32], Bs[128 * 32];
  const int z = blockIdx.z;
  const ushort* A  = (z == 0) ? Xq : (z == 1) ? Xk : Xv;
  const ushort* Bp = (z == 0) ? Wtq : (z == 1) ? Wtk : Wtv;
  const float* bias = (z == 0) ? bq : (z == 1) ? bk : bv;
  void* out = (z == 0) ? (void*)Qh : (z == 1) ? (void*)Kh : (void*)Vt;
  gemm_core(A, Bp, bias, out, (z == 2) ? 1 : 0, As, Bs);
}

__global__ __launch_bounds__(256) void gemm_o(
    const ushort* __restrict__ Obf, const ushort* __restrict__ Wto,
    const float* __restrict__ bo, float* __restrict__ out) {
  __shared__ ushort As[128 * 32], Bs[128 * 32];
  gemm_core(Obf, Wto, bo, out, 2, As, Bs);
}

// ---------------- flash attention ----------------
// grid = 32 bh * 16 qblocks; block = 4 waves; wave handles 32 q rows.
// Swapped QK^T: C = K_tile x Q^T -> lane holds S[q = ql (+16*qi)][kv spread].
__global__ __launch_bounds__(256, 2) void attn(
    const ushort* __restrict__ Qh, const ushort* __restrict__ Kh,
    const ushort* __restrict__ Vt, const float* __restrict__ mask,
    const int* __restrict__ flagp, ushort* __restrict__ Obf) {
  __shared__ ushort Pl[4][32 * 64];                // per-wave P tile, XOR-swizzled
  const int bid = blockIdx.x;
  const int bh = bid >> 4, qb = bid & 15;
  const int tid = threadIdx.x, lane = tid & 63, wave = tid >> 6;
  const int ql = lane & 15, lg = lane >> 4;
  const int q0 = qb * 128 + wave * 32;
  const bool um = (*flagp) != 0;
  const ushort* Kb = Kh + (size_t)bh * S_LEN * DH;
  const ushort* Vb = Vt + (size_t)bh * DH * S_LEN;
  ushort* Pw = Pl[wave];
  const unsigned swz = (unsigned)((ql & 7) << 4);

  F8 qf[2][2];                                     // [q-frag][k-half]
#pragma unroll
  for (int qi = 0; qi < 2; ++qi) {
    const ushort* qp = Qh + ((size_t)bh * S_LEN + q0 + qi * 16 + ql) * DH + lg * 8;
    qf[qi][0].s = *(const s8v*)qp;
    qf[qi][1].s = *(const s8v*)(qp + 32);
  }

  float mrun[2] = {-1e30f, -1e30f}, lrun[2] = {0.f, 0.f};
  f4 oacc[4][2] = {};                              // [d-tile][q-frag]

  for (int kt = 0; kt < 32; ++kt) {
    const int kv0 = kt * 64;
    float s[4][2][4];
#pragma unroll
    for (int t = 0; t < 4; ++t) {
      const ushort* kp = Kb + (size_t)(kv0 + t * 16 + ql) * DH + lg * 8;
      F8 k0, k1;
      k0.s = *(const s8v*)kp;
      k1.s = *(const s8v*)(kp + 32);
#pragma unroll
      for (int qi = 0; qi < 2; ++qi) {
        f4 c = {};
        c = __builtin_amdgcn_mfma_f32_16x16x32_bf16(k0.b, qf[qi][0].b, c, 0, 0, 0);
        c = __builtin_amdgcn_mfma_f32_16x16x32_bf16(k1.b, qf[qi][1].b, c, 0, 0, 0);
#pragma unroll
        for (int r = 0; r < 4; ++r) s[t][qi][r] = c[r] * 0.125f;
      }
    }
    if (um) {
#pragma unroll
      for (int t = 0; t < 4; ++t)
#pragma unroll
        for (int qi = 0; qi < 2; ++qi)
#pragma unroll
          for (int r = 0; r < 4; ++r)
            s[t][qi][r] += mask[(size_t)(q0 + qi * 16 + ql) * S_LEN +
                                kv0 + t * 16 + lg * 4 + r] * (-1e9f);
    }
#pragma unroll
    for (int qi = 0; qi < 2; ++qi) {
      float mt = s[0][qi][0];
#pragma unroll
      for (int t = 0; t < 4; ++t)
#pragma unroll
        for (int r = 0; r < 4; ++r) mt = fmaxf(mt, s[t][qi][r]);
      mt = fmaxf(mt, __shfl_xor(mt, 16));
      mt = fmaxf(mt, __shfl_xor(mt, 32));
      const float mnew = fmaxf(mrun[qi], mt);
      const float alpha = __expf(mrun[qi] - mnew);
      float rs = 0.f;
#pragma unroll
      for (int t = 0; t < 4; ++t)
#pragma unroll
        for (int r = 0; r < 4; ++r) {
          s[t][qi][r] = __expf(s[t][qi][r] - mnew);
          rs += s[t][qi][r];
        }
      rs += __shfl_xor(rs, 16);
      rs += __shfl_xor(rs, 32);
      lrun[qi] = lrun[qi] * alpha + rs;
      mrun[qi] = mnew;
#pragma unroll
      for (int t = 0; t < 4; ++t)
#pragma unroll
        for (int r = 0; r < 4; ++r) oacc[t][qi][r] *= alpha;
    }
    // P -> LDS (bf16, row = qi*16+ql, XOR-swizzled on byte bit4)
#pragma unroll
    for (int qi = 0; qi < 2; ++qi)
#pragma unroll
      for (int t = 0; t < 4; ++t) {
        const unsigned byte0 =
            ((unsigned)((qi * 16 + ql) * 128 + (t * 16 + lg * 4) * 2)) ^ swz;
        *(unsigned*)((char*)Pw + byte0)     = pack2(s[t][qi][0], s[t][qi][1]);
        *(unsigned*)((char*)Pw + byte0 + 4) = pack2(s[t][qi][2], s[t][qi][3]);
      }
    // PV: B-frags from LDS, A-frags = V^T rows from global
    F8 pb[2][2];
#pragma unroll
    for (int qi = 0; qi < 2; ++qi)
#pragma unroll
      for (int h = 0; h < 2; ++h)
        pb[qi][h].s = *(const s8v*)((char*)Pw +
            ((((unsigned)((qi * 16 + ql) * 128 + h * 64 + lg * 16))) ^ swz));
#pragma unroll
    for (int t = 0; t < 4; ++t) {
      const ushort* vp = Vb + (size_t)(t * 16 + ql) * S_LEN + kv0 + lg * 8;
      F8 v0, v1;
      v0.s = *(const s8v*)vp;
      v1.s = *(const s8v*)(vp + 32);
#pragma unroll
      for (int qi = 0; qi < 2; ++qi) {
        oacc[t][qi] = __builtin_amdgcn_mfma_f32_16x16x32_bf16(v0.b, pb[qi][0].b,
                                                              oacc[t][qi], 0, 0, 0);
        oacc[t][qi] = __builtin_amdgcn_mfma_f32_16x16x32_bf16(v1.b, pb[qi][1].b,
                                                              oacc[t][qi], 0, 0, 0);
      }
    }
  }
  const int b = bh >> 3, h = bh & 7;
#pragma unroll
  for (int qi = 0; qi < 2; ++qi) {
    const float inv = 1.f / lrun[qi];
    const int qg = q0 + qi * 16 + ql;
#pragma unroll
    for (int t = 0; t < 4; ++t) {
      const int d0 = t * 16 + lg * 4;
      ushort* op = Obf + ((size_t)(b * S_LEN + qg)) * DM + h * DH + d0;
      *(unsigned*)op       = pack2(oacc[t][qi][0] * inv, oacc[t][qi][1] * inv);
      *(unsigned*)(op + 2) = pack2(oacc[t][qi][2] * inv, oacc[t][qi][3] * inv);
    }
  }
}

// ---------------- launch ----------------
extern "C" void kernel_launch(void* const* d_in, const int* in_sizes, int n_in,
                              void* d_out, int out_size, void* d_ws, size_t ws_size,
                              hipStream_t stream) {
  (void)in_sizes; (void)n_in; (void)out_size; (void)ws_size;
  const float* q    = (const float*)d_in[0];
  const float* k    = (const float*)d_in[1];
  const float* v    = (const float*)d_in[2];
  const float* mask = (const float*)d_in[3];
  const float* wq   = (const float*)d_in[4];
  const float* bq   = (const float*)d_in[5];
  const float* wk   = (const float*)d_in[6];
  const float* bk   = (const float*)d_in[7];
  const float* wv   = (const float*)d_in[8];
  const float* bv   = (const float*)d_in[9];
  const float* wo   = (const float*)d_in[10];
  const float* bo   = (const float*)d_in[11];

  char* ws = (char*)d_ws;
  const size_t SZX = (size_t)8192 * 512 * 2;       // 8 MB bf16 activation
  ushort* Xq  = (ushort*)(ws + 0 * SZX);
  ushort* Xk  = (ushort*)(ws + 1 * SZX);
  ushort* Xv  = (ushort*)(ws + 2 * SZX);
  ushort* Qh  = (ushort*)(ws + 3 * SZX);
  ushort* Kh  = (ushort*)(ws + 4 * SZX);
  ushort* Vt  = (ushort*)(ws + 5 * SZX);
  ushort* Obf = Xq;                                // reuse: Xq dead after QKV GEMM
  const size_t SZW = (size_t)512 * 512 * 2;
  ushort* Wtq = (ushort*)(ws + 6 * SZX + 0 * SZW);
  ushort* Wtk = (ushort*)(ws + 6 * SZX + 1 * SZW);
  ushort* Wtv = (ushort*)(ws + 6 * SZX + 2 * SZW);
  ushort* Wto = (ushort*)(ws + 6 * SZX + 3 * SZW);
  int* flag   = (int*)(ws + 6 * SZX + 4 * SZW);

  hipMemsetAsync(flag, 0, 4, stream);
  mask_scan<<<4096, 256, 0, stream>>>(mask, flag);
  cvt3<<<dim3(2048, 3), 256, 0, stream>>>(q, k, v, Xq, Xk, Xv);
  wtrans<<<dim3(16, 16, 4), dim3(32, 8), 0, stream>>>(wq, wk, wv, wo,
                                                      Wtq, Wtk, Wtv, Wto);
  gemm_qkv<<<dim3(64, 4, 3), 256, 0, stream>>>(Xq, Xk, Xv, Wtq, Wtk, Wtv,
                                               bq, bk, bv, Qh, Kh, Vt);
  attn<<<512, 256, 0, stream>>>(Qh, Kh, Vt, mask, flag, Obf);
  gemm_o<<<dim3(64, 4), 256, 0, stream>>>(Obf, Wto, bo, (float*)d_out);
}

// Round 2
// 141.479 us; speedup vs baseline: 1.4040x; 1.4040x over previous
//
#include <hip/hip_runtime.h>
#include <hip/hip_bf16.h>

#define S_LEN 2048
#define DM    512
#define NH    8
#define DH    64

typedef float  f4  __attribute__((ext_vector_type(4)));
typedef short  s8v __attribute__((ext_vector_type(8)));
typedef __bf16 b8v __attribute__((ext_vector_type(8)));
union F8 { s8v s; b8v b; };

typedef __attribute__((address_space(1))) const void gas_t;
typedef __attribute__((address_space(3))) void       las_t;

__device__ __forceinline__ void gl16(const void* g, void* l) {
  __builtin_amdgcn_global_load_lds((gas_t*)g, (las_t*)l, 16, 0, 0);
}

__device__ __forceinline__ ushort f2bf(float x) {
  unsigned u = __float_as_uint(x);
  u += 0x7FFFu + ((u >> 16) & 1u);   // round-to-nearest-even
  return (ushort)(u >> 16);
}
__device__ __forceinline__ unsigned pack2(float a, float b) {
  return (unsigned)f2bf(a) | ((unsigned)f2bf(b) << 16);
}

// ---------------- mask scan: flag = any(mask != 0) ----------------
__global__ void mask_scan(const float* __restrict__ m, int* __restrict__ flag) {
  const int i = blockIdx.x * 256 + threadIdx.x;
  const float4 v = ((const float4*)m)[i];
  const bool nz = (v.x != 0.f) | (v.y != 0.f) | (v.z != 0.f) | (v.w != 0.f);
  if (nz) atomicOr(flag, 1);
}

// ---------------- fp32 -> bf16 convert (q,k,v) ----------------
__global__ void cvt3(const float* __restrict__ q, const float* __restrict__ k,
                     const float* __restrict__ v, ushort* __restrict__ oq,
                     ushort* __restrict__ ok, ushort* __restrict__ ov) {
  const int z = blockIdx.y;
  const float* s = (z == 0) ? q : (z == 1) ? k : v;
  ushort* d = (z == 0) ? oq : (z == 1) ? ok : ov;
  const size_t i = ((size_t)blockIdx.x * 256 + threadIdx.x) * 8;
  const float4 a = *(const float4*)(s + i);
  const float4 b = *(const float4*)(s + i + 4);
  s8v r;
  r[0] = (short)f2bf(a.x); r[1] = (short)f2bf(a.y);
  r[2] = (short)f2bf(a.z); r[3] = (short)f2bf(a.w);
  r[4] = (short)f2bf(b.x); r[5] = (short)f2bf(b.y);
  r[6] = (short)f2bf(b.z); r[7] = (short)f2bf(b.w);
  *(s8v*)(d + i) = r;
}

// ------------- weight transpose+convert: Wt[n][k] = bf16(W[k][n]) -------------
__global__ void wtrans(const float* __restrict__ w0, const float* __restrict__ w1,
                       const float* __restrict__ w2, const float* __restrict__ w3,
                       ushort* __restrict__ o0, ushort* __restrict__ o1,
                       ushort* __restrict__ o2, ushort* __restrict__ o3) {
  const int z = blockIdx.z;
  const float* src = (z == 0) ? w0 : (z == 1) ? w1 : (z == 2) ? w2 : w3;
  ushort* dst = (z == 0) ? o0 : (z == 1) ? o1 : (z == 2) ? o2 : o3;
  __shared__ float tile[32][33];
  const int tx = threadIdx.x, ty = threadIdx.y;    // 32 x 8
  const int k0 = blockIdx.x * 32, n0 = blockIdx.y * 32;
#pragma unroll
  for (int i = 0; i < 4; ++i)
    tile[ty + i * 8][tx] = src[(size_t)(k0 + ty + i * 8) * DM + n0 + tx];
  __syncthreads();
#pragma unroll
  for (int i = 0; i < 4; ++i)
    dst[(size_t)(n0 + ty + i * 8) * DM + k0 + tx] = f2bf(tile[tx][ty + i * 8]);
}

// ---------------- 128x128 bf16 MFMA GEMM core (M=8192,N=512,K=512) ----------------
__device__ __forceinline__ void gemm_core(
    const ushort* __restrict__ A, const ushort* __restrict__ Bt,
    const float* __restrict__ bias, void* __restrict__ out, int mode,
    ushort* As, ushort* Bs) {
  const int tid  = threadIdx.x;
  const int lane = tid & 63, wave = tid >> 6;
  const int ql = lane & 15, lg = lane >> 4;
  const int wr = wave >> 1, wc = wave & 1;
  const int tm = blockIdx.x, tn = blockIdx.y;

  const int srow  = wave * 32 + (lane >> 2);
  const int sbyte = (lane & 3) * 16;

  const char* gA = (const char*)(A  + (size_t)(tm * 128 + srow) * 512) + sbyte;
  const char* gB = (const char*)(Bt + (size_t)(tn * 128 + srow) * 512) + sbyte;
  char* lA = (char*)As + wave * 2048;
  char* lB = (char*)Bs + wave * 2048;

  f4 acc[4][4] = {};

  for (int kt = 0; kt < 16; ++kt) {
    const size_t gofs = (size_t)kt * 64;
    gl16(gA + gofs, lA);
    gl16(gA + gofs + 16 * 512 * 2, lA + 1024);
    gl16(gB + gofs, lB);
    gl16(gB + gofs + 16 * 512 * 2, lB + 1024);
    __syncthreads();
    F8 af[4], bf[4];
#pragma unroll
    for (int i = 0; i < 4; ++i) {
      af[i].s = *(const s8v*)(As + (wr * 64 + i * 16 + ql) * 32 + lg * 8);
      bf[i].s = *(const s8v*)(Bs + (wc * 64 + i * 16 + ql) * 32 + lg * 8);
    }
#pragma unroll
    for (int i = 0; i < 4; ++i)
#pragma unroll
      for (int j = 0; j < 4; ++j)
        acc[i][j] = __builtin_amdgcn_mfma_f32_16x16x32_bf16(af[i].b, bf[j].b,
                                                            acc[i][j], 0, 0, 0);
    __syncthreads();
  }

#pragma unroll
  for (int i = 0; i < 4; ++i) {
#pragma unroll
    for (int j = 0; j < 4; ++j) {
      const int n = tn * 128 + wc * 64 + j * 16 + ql;
      const float bz = bias[n];
#pragma unroll
      for (int r = 0; r < 4; ++r) {
        const int m = tm * 128 + wr * 64 + i * 16 + lg * 4 + r;
        const float val = acc[i][j][r] + bz;
        if (mode == 2) {
          ((float*)out)[(size_t)m * DM + n] = val;
        } else {
          const int b = m >> 11, s = m & 2047, h = n >> 6, d = n & 63;
          if (mode == 0)
            ((ushort*)out)[((size_t)(b * NH + h) * S_LEN + s) * DH + d] = f2bf(val);
          else
            ((ushort*)out)[((size_t)(b * NH + h) * DH + d) * S_LEN + s] = f2bf(val);
        }
      }
    }
  }
}

__global__ __launch_bounds__(256) void gemm_qkv(
    const ushort* __restrict__ Xq, const ushort* __restrict__ Xk,
    const ushort* __restrict__ Xv, const ushort* __restrict__ Wtq,
    const ushort* __restrict__ Wtk, const ushort* __restrict__ Wtv,
    const float* __restrict__ bq, const float* __restrict__ bk,
    const float* __restrict__ bv, ushort* __restrict__ Qh,
    ushort* __restrict__ Kh, ushort* __restrict__ Vt) {
  __shared__ ushort As[128 * 32], Bs[128 * 32];
  const int z = blockIdx.z;
  const ushort* A  = (z == 0) ? Xq : (z == 1) ? Xk : Xv;
  const ushort* Bp = (z == 0) ? Wtq : (z == 1) ? Wtk : Wtv;
  const float* bias = (z == 0) ? bq : (z == 1) ? bk : bv;
  void* out = (z == 0) ? (void*)Qh : (z == 1) ? (void*)Kh : (void*)Vt;
  gemm_core(A, Bp, bias, out, (z == 2) ? 1 : 0, As, Bs);
}

__global__ __launch_bounds__(256) void gemm_o(
    const ushort* __restrict__ Obf, const ushort* __restrict__ Wto,
    const float* __restrict__ bo, float* __restrict__ out) {
  __shared__ ushort As[128 * 32], Bs[128 * 32];
  gemm_core(Obf, Wto, bo, out, 2, As, Bs);
}

// ---------------- flash attention (LDS-staged K/V, 2-phase pipeline) ----------------
// grid = 512 (XCD-remapped to 32 bh * 16 qblocks); 4 waves; wave = 32 q rows.
// K tile [64][64] bf16 and V^T tile [64][64] staged in LDS, double-buffered,
// XOR-swizzled (unit ^= row&7) via pre-swizzled global_load_lds source.
__global__ __launch_bounds__(256, 2) void attn(
    const ushort* __restrict__ Qh, const ushort* __restrict__ Kh,
    const ushort* __restrict__ Vt, const float* __restrict__ mask,
    const int* __restrict__ flagp, ushort* __restrict__ Obf) {
  __shared__ ushort Ks[2][4096];                   // 2 x 8KB
  __shared__ ushort Vs[2][4096];                   // 2 x 8KB
  __shared__ ushort Pl[4][2048];                   // per-wave P tile, 4 x 4KB

  // XCD-aware remap: 16 consecutive qblocks (same bh group) per XCD
  const int bid = (blockIdx.x & 7) * 64 + (blockIdx.x >> 3);
  const int bh = bid >> 4, qb = bid & 15;
  const int tid = threadIdx.x, lane = tid & 63, wave = tid >> 6;
  const int ql = lane & 15, lg = lane >> 4;
  const int q0 = qb * 128 + wave * 32;
  const bool um = (*flagp) != 0;
  const char* KbC = (const char*)(Kh + (size_t)bh * S_LEN * DH);
  const char* VbC = (const char*)(Vt + (size_t)bh * DH * S_LEN);
  ushort* Pw = Pl[wave];
  const unsigned swz = (unsigned)((ql & 7) << 4);

  // staging source offsets (pre-swizzled so linear LDS fill == swizzled layout)
  int kofs[2], vofs[2];
#pragma unroll
  for (int c = 0; c < 2; ++c) {
    const int ui  = wave * 128 + c * 64 + lane;    // 16B-unit index in 8KB tile
    const int row = ui >> 3, u = ui & 7;
    const int xu  = u ^ (row & 7);
    kofs[c] = row * 128  + (xu << 4);              // K rows are 128B
    vofs[c] = row * 4096 + (xu << 4);              // V^T rows are S*2 = 4096B
  }

  // fragment ds_read offsets: row r -> r*128 + ((h*4+lg)<<4 ^ (ql&7)<<4)
  const unsigned hoff0 = ((unsigned)(lg << 4)) ^ swz;
  const unsigned hoff1 = ((unsigned)((4 + lg) << 4)) ^ swz;

  F8 qf[2][2];
#pragma unroll
  for (int qi = 0; qi < 2; ++qi) {
    const ushort* qp = Qh + ((size_t)bh * S_LEN + q0 + qi * 16 + ql) * DH + lg * 8;
    qf[qi][0].s = *(const s8v*)qp;
    qf[qi][1].s = *(const s8v*)(qp + 32);
  }

  float mrun[2] = {-1e30f, -1e30f}, lrun[2] = {0.f, 0.f};
  f4 oacc[4][2] = {};

  // prologue: stage tile 0
  {
    char* kl = (char*)&Ks[0][0] + wave * 2048;
    char* vl = (char*)&Vs[0][0] + wave * 2048;
    gl16(KbC + kofs[0], kl);
    gl16(KbC + kofs[1], kl + 1024);
    gl16(VbC + vofs[0], vl);
    gl16(VbC + vofs[1], vl + 1024);
  }
  __syncthreads();

  int cur = 0;
  for (int kt = 0; kt < 32; ++kt) {
    // issue next tile's staging loads (latency hides under compute below)
    if (kt + 1 < 32) {
      const char* kg = KbC + (size_t)(kt + 1) * 8192;   // 64 rows * 128B
      const char* vg = VbC + (size_t)(kt + 1) * 128;    // 64 cols * 2B
      char* kl = (char*)&Ks[cur ^ 1][0] + wave * 2048;
      char* vl = (char*)&Vs[cur ^ 1][0] + wave * 2048;
      gl16(kg + kofs[0], kl);
      gl16(kg + kofs[1], kl + 1024);
      gl16(vg + vofs[0], vl);
      gl16(vg + vofs[1], vl + 1024);
    }

    const int kv0 = kt * 64;
    const char* KtB = (const char*)&Ks[cur][0];
    const char* VtB = (const char*)&Vs[cur][0];
    float s[4][2][4];

    __builtin_amdgcn_s_setprio(1);
#pragma unroll
    for (int t = 0; t < 4; ++t) {
      const unsigned rb = (unsigned)((t * 16 + ql) * 128);
      F8 k0, k1;
      k0.s = *(const s8v*)(KtB + rb + hoff0);
      k1.s = *(const s8v*)(KtB + rb + hoff1);
#pragma unroll
      for (int qi = 0; qi < 2; ++qi) {
        f4 c = {};
        c = __builtin_amdgcn_mfma_f32_16x16x32_bf16(k0.b, qf[qi][0].b, c, 0, 0, 0);
        c = __builtin_amdgcn_mfma_f32_16x16x32_bf16(k1.b, qf[qi][1].b, c, 0, 0, 0);
#pragma unroll
        for (int r = 0; r < 4; ++r) s[t][qi][r] = c[r] * 0.125f;
      }
    }
    __builtin_amdgcn_s_setprio(0);

    if (um) {
#pragma unroll
      for (int t = 0; t < 4; ++t)
#pragma unroll
        for (int qi = 0; qi < 2; ++qi)
#pragma unroll
          for (int r = 0; r < 4; ++r)
            s[t][qi][r] += mask[(size_t)(q0 + qi * 16 + ql) * S_LEN +
                                kv0 + t * 16 + lg * 4 + r] * (-1e9f);
    }
#pragma unroll
    for (int qi = 0; qi < 2; ++qi) {
      float mt = s[0][qi][0];
#pragma unroll
      for (int t = 0; t < 4; ++t)
#pragma unroll
        for (int r = 0; r < 4; ++r) mt = fmaxf(mt, s[t][qi][r]);
      mt = fmaxf(mt, __shfl_xor(mt, 16));
      mt = fmaxf(mt, __shfl_xor(mt, 32));
      const float mnew = fmaxf(mrun[qi], mt);
      const float alpha = __expf(mrun[qi] - mnew);
      float rs = 0.f;
#pragma unroll
      for (int t = 0; t < 4; ++t)
#pragma unroll
        for (int r = 0; r < 4; ++r) {
          s[t][qi][r] = __expf(s[t][qi][r] - mnew);
          rs += s[t][qi][r];
        }
      rs += __shfl_xor(rs, 16);
      rs += __shfl_xor(rs, 32);
      lrun[qi] = lrun[qi] * alpha + rs;
      mrun[qi] = mnew;
#pragma unroll
      for (int t = 0; t < 4; ++t)
#pragma unroll
        for (int r = 0; r < 4; ++r) oacc[t][qi][r] *= alpha;
    }

    // P -> LDS (bf16, 8B packed writes, XOR-swizzled)
#pragma unroll
    for (int qi = 0; qi < 2; ++qi)
#pragma unroll
      for (int t = 0; t < 4; ++t) {
        const unsigned byte0 =
            ((unsigned)((qi * 16 + ql) * 128 + t * 32 + lg * 8)) ^ swz;
        const unsigned long long w =
            (unsigned long long)pack2(s[t][qi][0], s[t][qi][1]) |
            ((unsigned long long)pack2(s[t][qi][2], s[t][qi][3]) << 32);
        *(unsigned long long*)((char*)Pw + byte0) = w;
      }

    F8 pb[2][2];
#pragma unroll
    for (int qi = 0; qi < 2; ++qi)
#pragma unroll
      for (int h = 0; h < 2; ++h)
        pb[qi][h].s = *(const s8v*)((char*)Pw +
            (((unsigned)((qi * 16 + ql) * 128 + h * 64 + lg * 16)) ^ swz));

    __builtin_amdgcn_s_setprio(1);
#pragma unroll
    for (int t = 0; t < 4; ++t) {
      const unsigned rb = (unsigned)((t * 16 + ql) * 128);
      F8 v0, v1;
      v0.s = *(const s8v*)(VtB + rb + hoff0);
      v1.s = *(const s8v*)(VtB + rb + hoff1);
#pragma unroll
      for (int qi = 0; qi < 2; ++qi) {
        oacc[t][qi] = __builtin_amdgcn_mfma_f32_16x16x32_bf16(v0.b, pb[qi][0].b,
                                                              oacc[t][qi], 0, 0, 0);
        oacc[t][qi] = __builtin_amdgcn_mfma_f32_16x16x32_bf16(v1.b, pb[qi][1].b,
                                                              oacc[t][qi], 0, 0, 0);
      }
    }
    __builtin_amdgcn_s_setprio(0);

    __syncthreads();
    cur ^= 1;
  }

  const int b = bh >> 3, h = bh & 7;
#pragma unroll
  for (int qi = 0; qi < 2; ++qi) {
    const float inv = 1.f / lrun[qi];
    const int qg = q0 + qi * 16 + ql;
#pragma unroll
    for (int t = 0; t < 4; ++t) {
      const int d0 = t * 16 + lg * 4;
      ushort* op = Obf + ((size_t)(b * S_LEN + qg)) * DM + h * DH + d0;
      *(unsigned*)op       = pack2(oacc[t][qi][0] * inv, oacc[t][qi][1] * inv);
      *(unsigned*)(op + 2) = pack2(oacc[t][qi][2] * inv, oacc[t][qi][3] * inv);
    }
  }
}

// ---------------- launch ----------------
extern "C" void kernel_launch(void* const* d_in, const int* in_sizes, int n_in,
                              void* d_out, int out_size, void* d_ws, size_t ws_size,
                              hipStream_t stream) {
  (void)in_sizes; (void)n_in; (void)out_size; (void)ws_size;
  const float* q    = (const float*)d_in[0];
  const float* k    = (const float*)d_in[1];
  const float* v    = (const float*)d_in[2];
  const float* mask = (const float*)d_in[3];
  const float* wq   = (const float*)d_in[4];
  const float* bq   = (const float*)d_in[5];
  const float* wk   = (const float*)d_in[6];
  const float* bk   = (const float*)d_in[7];
  const float* wv   = (const float*)d_in[8];
  const float* bv   = (const float*)d_in[9];
  const float* wo   = (const float*)d_in[10];
  const float* bo   = (const float*)d_in[11];

  char* ws = (char*)d_ws;
  const size_t SZX = (size_t)8192 * 512 * 2;
  ushort* Xq  = (ushort*)(ws + 0 * SZX);
  ushort* Xk  = (ushort*)(ws + 1 * SZX);
  ushort* Xv  = (ushort*)(ws + 2 * SZX);
  ushort* Qh  = (ushort*)(ws + 3 * SZX);
  ushort* Kh  = (ushort*)(ws + 4 * SZX);
  ushort* Vt  = (ushort*)(ws + 5 * SZX);
  ushort* Obf = Xq;
  const size_t SZW = (size_t)512 * 512 * 2;
  ushort* Wtq = (ushort*)(ws + 6 * SZX + 0 * SZW);
  ushort* Wtk = (ushort*)(ws + 6 * SZX + 1 * SZW);
  ushort* Wtv = (ushort*)(ws + 6 * SZX + 2 * SZW);
  ushort* Wto = (ushort*)(ws + 6 * SZX + 3 * SZW);
  int* flag   = (int*)(ws + 6 * SZX + 4 * SZW);

  hipMemsetAsync(flag, 0, 4, stream);
  mask_scan<<<4096, 256, 0, stream>>>(mask, flag);
  cvt3<<<dim3(2048, 3), 256, 0, stream>>>(q, k, v, Xq, Xk, Xv);
  wtrans<<<dim3(16, 16, 4), dim3(32, 8), 0, stream>>>(wq, wk, wv, wo,
                                                      Wtq, Wtk, Wtv, Wto);
  gemm_qkv<<<dim3(64, 4, 3), 256, 0, stream>>>(Xq, Xk, Xv, Wtq, Wtk, Wtv,
                                               bq, bk, bv, Qh, Kh, Vt);
  attn<<<512, 256, 0, stream>>>(Qh, Kh, Vt, mask, flag, Obf);
  gemm_o<<<dim3(64, 4), 256, 0, stream>>>(Obf, Wto, bo, (float*)d_out);
}